// Round 2
// baseline (736.623 us; speedup 1.0000x reference)
//
#include <hip/hip_runtime.h>
#include <math.h>

#define N_NODES 50000
#define IN_F 256
#define OUT_F 64

// ---------------------------------------------------------------------------
// Workspace layout (all 4-byte elements):
//   sup      : float[N_NODES*OUT_F]   (12.8 MB)  projected features
//   hist     : int[N_NODES]           degree histogram
//   row_ptr  : int[N_NODES+1]         CSR offsets
//   cursor   : int[N_NODES]           scatter cursors (copy of row_ptr)
//   ecol_s   : int[E]                 edge cols sorted by row
//   ew_s     : float[E]               edge weights sorted by row
// total ~26.3 MB
// ---------------------------------------------------------------------------

// ---- zero the histogram ----
__global__ __launch_bounds__(256) void zero_hist_kernel(int* __restrict__ hist, int n) {
    int i = blockIdx.x * 256 + threadIdx.x;
    if (i < n) hist[i] = 0;
}

// ---- degree histogram over edge rows ----
__global__ __launch_bounds__(256) void hist_kernel(const int* __restrict__ erow,
                                                   int* __restrict__ hist, int E) {
    int e = blockIdx.x * 256 + threadIdx.x;
    if (e < E) atomicAdd(&hist[erow[e]], 1);
}

// ---- single-block exclusive scan of hist -> row_ptr (+ cursor copy) ----
__global__ __launch_bounds__(1024) void scan_kernel(const int* __restrict__ hist,
                                                    int* __restrict__ row_ptr,
                                                    int* __restrict__ cursor, int E) {
    __shared__ int part[1024];
    const int t = threadIdx.x;
    const int CH = (N_NODES + 1023) / 1024;  // 49
    const int base = t * CH;
    int s = 0;
    for (int i = 0; i < CH; ++i) {
        int idx = base + i;
        if (idx < N_NODES) s += hist[idx];
    }
    part[t] = s;
    __syncthreads();
    // Hillis-Steele inclusive scan over 1024 partials
    for (int off = 1; off < 1024; off <<= 1) {
        int v = (t >= off) ? part[t - off] : 0;
        __syncthreads();
        part[t] += v;
        __syncthreads();
    }
    int run = (t == 0) ? 0 : part[t - 1];  // exclusive base for this chunk
    for (int i = 0; i < CH; ++i) {
        int idx = base + i;
        if (idx < N_NODES) {
            row_ptr[idx] = run;
            cursor[idx]  = run;
            run += hist[idx];
        }
    }
    if (t == 1023) row_ptr[N_NODES] = E;
}

// ---- permute (col, w) into row-sorted order ----
__global__ __launch_bounds__(256) void permute_kernel(const int* __restrict__ erow,
                                                      const int* __restrict__ ecol,
                                                      const float* __restrict__ ew,
                                                      int* __restrict__ cursor,
                                                      int* __restrict__ ecol_s,
                                                      float* __restrict__ ew_s, int E) {
    int e = blockIdx.x * 256 + threadIdx.x;
    if (e >= E) return;
    int r = erow[e];
    int pos = atomicAdd(&cursor[r], 1);
    ecol_s[pos] = ecol[e];
    ew_s[pos]   = ew[e];
}

// ---- dense projection: support = features @ W ----
// 4 waves/block, 16 rows per wave, lane = output col. W lives in LDS.
// Feature-row pointers are wave-uniform -> compiler can scalarize the float4
// feature loads into s_load_dwordx4; per 4-k chunk: 4 LDS b32 + 64 FMA.
__global__ __launch_bounds__(256) void gemm_kernel(const float* __restrict__ feat,
                                                   const float* __restrict__ W,
                                                   float* __restrict__ sup) {
    __shared__ float wl[IN_F * OUT_F];  // 64 KB
    for (int i = threadIdx.x; i < IN_F * OUT_F; i += 256) wl[i] = W[i];
    __syncthreads();

    const int col  = threadIdx.x & 63;
    const int warp = __builtin_amdgcn_readfirstlane(threadIdx.x >> 6);
    const int row0 = blockIdx.x * 64 + warp * 16;

    const float4* fp[16];
#pragma unroll
    for (int r = 0; r < 16; ++r) {
        int row = row0 + r;
        row = row < N_NODES ? row : N_NODES - 1;  // clamp reads, guard writes
        fp[r] = (const float4*)(feat + (size_t)row * IN_F);
    }

    float acc[16];
#pragma unroll
    for (int r = 0; r < 16; ++r) acc[r] = 0.f;

    for (int kc = 0; kc < IN_F / 4; ++kc) {
        const float w0 = wl[(4 * kc + 0) * OUT_F + col];
        const float w1 = wl[(4 * kc + 1) * OUT_F + col];
        const float w2 = wl[(4 * kc + 2) * OUT_F + col];
        const float w3 = wl[(4 * kc + 3) * OUT_F + col];
#pragma unroll
        for (int r = 0; r < 16; ++r) {
            float4 f = fp[r][kc];
            acc[r] += f.x * w0 + f.y * w1 + f.z * w2 + f.w * w3;
        }
    }

#pragma unroll
    for (int r = 0; r < 16; ++r) {
        int row = row0 + r;
        if (row < N_NODES) sup[(size_t)row * OUT_F + col] = acc[r];
    }
}

// ---- CSR gather-reduce + fused tanh: out[r] = tanh(sum_j w_j * sup[col_j]) ----
// One wave per destination row; lane = output column; register accumulator;
// single coalesced 256B store. No atomics anywhere.
__global__ __launch_bounds__(256) void reduce_kernel(const float* __restrict__ sup,
                                                     const int* __restrict__ row_ptr,
                                                     const int* __restrict__ ecol_s,
                                                     const float* __restrict__ ew_s,
                                                     const int* __restrict__ active,
                                                     float* __restrict__ out) {
    int wid = (blockIdx.x * 256 + threadIdx.x) >> 6;
    if (wid >= N_NODES) return;
    const int lane = threadIdx.x & 63;
    const int s = row_ptr[wid];
    const int e = row_ptr[wid + 1];

    float acc = 0.f;
    int j = s;
    for (; j + 1 < e; j += 2) {
        int   c0 = ecol_s[j],     c1 = ecol_s[j + 1];
        float w0 = ew_s[j],       w1 = ew_s[j + 1];
        acc += w0 * sup[(size_t)c0 * OUT_F + lane];
        acc += w1 * sup[(size_t)c1 * OUT_F + lane];
    }
    if (j < e) {
        acc += ew_s[j] * sup[(size_t)ecol_s[j] * OUT_F + lane];
    }

    float v = (*active) ? tanhf(acc) : acc;
    out[(size_t)wid * OUT_F + lane] = v;
}

extern "C" void kernel_launch(void* const* d_in, const int* in_sizes, int n_in,
                              void* d_out, int out_size, void* d_ws, size_t ws_size,
                              hipStream_t stream) {
    const float* feat = (const float*)d_in[0];
    const float* W    = (const float*)d_in[1];
    const int*   erow = (const int*)d_in[2];
    const int*   ecol = (const int*)d_in[3];
    const float* ew   = (const float*)d_in[4];
    const int*   act  = (const int*)d_in[5];
    float* out = (float*)d_out;

    const int E = in_sizes[2];

    // workspace carve-up
    char* ws = (char*)d_ws;
    float* sup     = (float*)ws;                       ws += (size_t)N_NODES * OUT_F * 4;
    int*   hist    = (int*)ws;                         ws += (size_t)N_NODES * 4;
    int*   row_ptr = (int*)ws;                         ws += (size_t)(N_NODES + 1) * 4;
    int*   cursor  = (int*)ws;                         ws += (size_t)N_NODES * 4;
    int*   ecol_s  = (int*)ws;                         ws += (size_t)E * 4;
    float* ew_s    = (float*)ws;

    // 1) CSR build
    zero_hist_kernel<<<(N_NODES + 255) / 256, 256, 0, stream>>>(hist, N_NODES);
    hist_kernel<<<(E + 255) / 256, 256, 0, stream>>>(erow, hist, E);
    scan_kernel<<<1, 1024, 0, stream>>>(hist, row_ptr, cursor, E);
    permute_kernel<<<(E + 255) / 256, 256, 0, stream>>>(erow, ecol, ew, cursor, ecol_s, ew_s, E);

    // 2) dense projection
    gemm_kernel<<<(N_NODES + 63) / 64, 256, 0, stream>>>(feat, W, sup);

    // 3) gather-reduce with fused tanh (writes every output row)
    reduce_kernel<<<(N_NODES * 64 + 255) / 256, 256, 0, stream>>>(sup, row_ptr, ecol_s, ew_s, act, out);
}

// Round 3
// 368.917 us; speedup vs baseline: 1.9967x; 1.9967x over previous
//
#include <hip/hip_runtime.h>
#include <math.h>

#define N_NODES 50000
#define IN_F 256
#define OUT_F 64
#define NBLK 196  // ceil(50000/256)

// ---------------------------------------------------------------------------
// Workspace layout (all 4-byte elements):
//   sup      : float[N_NODES*OUT_F]   projected features (12.8 MB)
//   hist     : int[N_NODES]           degree histogram
//   row_ptr  : int[N_NODES+1]         CSR offsets
//   cursor   : int[N_NODES]           scatter cursors
//   bsum     : int[256]               per-block partial sums
//   bscan    : int[256]               exclusive scan of bsum
//   ecol_s   : int[E]                 edge cols sorted by row
//   ew_s     : float[E]               edge weights sorted by row
// ---------------------------------------------------------------------------

__global__ __launch_bounds__(256) void zero_hist_kernel(int* __restrict__ hist, int n) {
    int i = blockIdx.x * 256 + threadIdx.x;
    if (i < n) hist[i] = 0;
}

__global__ __launch_bounds__(256) void hist_kernel(const int* __restrict__ erow,
                                                   int* __restrict__ hist, int E) {
    int e = blockIdx.x * 256 + threadIdx.x;
    if (e < E) atomicAdd(&hist[erow[e]], 1);
}

// ---- scan stage 1: per-block sums of 256 hist entries ----
__global__ __launch_bounds__(256) void partial_kernel(const int* __restrict__ hist,
                                                      int* __restrict__ bsum) {
    __shared__ int sh[256];
    int gid = blockIdx.x * 256 + threadIdx.x;
    sh[threadIdx.x] = (gid < N_NODES) ? hist[gid] : 0;
    __syncthreads();
    for (int off = 128; off > 0; off >>= 1) {
        if (threadIdx.x < off) sh[threadIdx.x] += sh[threadIdx.x + off];
        __syncthreads();
    }
    if (threadIdx.x == 0) bsum[blockIdx.x] = sh[0];
}

// ---- scan stage 2: exclusive scan of the 196 block sums (one block) ----
__global__ __launch_bounds__(256) void scan_bsum_kernel(const int* __restrict__ bsum,
                                                        int* __restrict__ bscan,
                                                        int* __restrict__ row_ptr) {
    __shared__ int sh[256];
    const int t = threadIdx.x;
    int v = (t < NBLK) ? bsum[t] : 0;
    sh[t] = v;
    __syncthreads();
    for (int off = 1; off < 256; off <<= 1) {
        int u = (t >= off) ? sh[t - off] : 0;
        __syncthreads();
        sh[t] += u;
        __syncthreads();
    }
    if (t < NBLK) bscan[t] = sh[t] - v;
    if (t == 255) row_ptr[N_NODES] = sh[255];  // total = E
}

// ---- scan stage 3: local exclusive scan + block offset -> row_ptr, cursor ----
__global__ __launch_bounds__(256) void scan_local_kernel(const int* __restrict__ hist,
                                                         const int* __restrict__ bscan,
                                                         int* __restrict__ row_ptr,
                                                         int* __restrict__ cursor) {
    __shared__ int sh[256];
    const int t = threadIdx.x;
    int gid = blockIdx.x * 256 + t;
    int v = (gid < N_NODES) ? hist[gid] : 0;
    sh[t] = v;
    __syncthreads();
    for (int off = 1; off < 256; off <<= 1) {
        int u = (t >= off) ? sh[t - off] : 0;
        __syncthreads();
        sh[t] += u;
        __syncthreads();
    }
    if (gid < N_NODES) {
        int val = bscan[blockIdx.x] + sh[t] - v;
        row_ptr[gid] = val;
        cursor[gid]  = val;
    }
}

// ---- permute (col, w) into row-sorted order ----
__global__ __launch_bounds__(256) void permute_kernel(const int* __restrict__ erow,
                                                      const int* __restrict__ ecol,
                                                      const float* __restrict__ ew,
                                                      int* __restrict__ cursor,
                                                      int* __restrict__ ecol_s,
                                                      float* __restrict__ ew_s, int E) {
    int e = blockIdx.x * 256 + threadIdx.x;
    if (e >= E) return;
    int r = erow[e];
    int pos = atomicAdd(&cursor[r], 1);
    ecol_s[pos] = ecol[e];
    ew_s[pos]   = ew[e];
}

// ---- tiled dense projection: support = features @ W ----
// Block 256 threads; output tile 128 rows x 64 cols; k staged in chunks of 16.
// LDS: A_s[128][18] (pad 18 -> conflict-free reads), B_s[16][64].
// Per thread: 8 rows x 4 cols micro-tile (32 FMA per k-step).
// Next chunk's global loads are prefetched into registers under compute.
__global__ __launch_bounds__(256) void gemm_kernel(const float* __restrict__ feat,
                                                   const float* __restrict__ W,
                                                   float* __restrict__ sup) {
    __shared__ float A_s[128 * 18];  // 9216 B
    __shared__ float B_s[16 * 64];   // 4096 B

    const int t = threadIdx.x;
    const int row0 = blockIdx.x * 128;
    const int tc = t & 15;   // col group: cols 4*tc .. 4*tc+3
    const int tr = t >> 4;   // row group: rows 8*tr .. 8*tr+7

    // staging assignment: A tile = 128 rows x 16 floats = 512 float4 (2/thread)
    const int ar = t >> 2;        // 0..63  (second f4 covers row ar+64)
    const int ac = t & 3;         // which float4 within the 16-float k-chunk

    int gr0 = row0 + ar;      if (gr0 >= N_NODES) gr0 = N_NODES - 1;
    int gr1 = row0 + ar + 64; if (gr1 >= N_NODES) gr1 = N_NODES - 1;
    const float4* gA0 = (const float4*)(feat + (size_t)gr0 * IN_F);
    const float4* gA1 = (const float4*)(feat + (size_t)gr1 * IN_F);
    const float4* gB  = (const float4*)W;   // B tile: k = t>>4, cols 4*tc..

    float acc[8][4];
#pragma unroll
    for (int r = 0; r < 8; ++r)
#pragma unroll
        for (int i = 0; i < 4; ++i) acc[r][i] = 0.f;

    // prefetch chunk 0
    float4 a0 = gA0[ac];
    float4 a1 = gA1[ac];
    float4 bb = gB[(t >> 4) * 16 + tc];

    for (int ch = 0; ch < 16; ++ch) {
        // regs -> LDS
        {
            float* ap0 = &A_s[ar * 18 + ac * 4];
            ap0[0] = a0.x; ap0[1] = a0.y; ap0[2] = a0.z; ap0[3] = a0.w;
            float* ap1 = &A_s[(ar + 64) * 18 + ac * 4];
            ap1[0] = a1.x; ap1[1] = a1.y; ap1[2] = a1.z; ap1[3] = a1.w;
            *(float4*)&B_s[(t >> 4) * 64 + tc * 4] = bb;
        }
        __syncthreads();

        // prefetch next chunk (stays in flight under compute)
        if (ch < 15) {
            a0 = gA0[(ch + 1) * 4 + ac];
            a1 = gA1[(ch + 1) * 4 + ac];
            bb = gB[((ch + 1) * 16 + (t >> 4)) * 16 + tc];
        }

#pragma unroll
        for (int k = 0; k < 16; ++k) {
            float b0 = B_s[k * 64 + tc * 4 + 0];
            float b1 = B_s[k * 64 + tc * 4 + 1];
            float b2 = B_s[k * 64 + tc * 4 + 2];
            float b3 = B_s[k * 64 + tc * 4 + 3];
#pragma unroll
            for (int r = 0; r < 8; ++r) {
                float av = A_s[(tr * 8 + r) * 18 + k];
                acc[r][0] += av * b0;
                acc[r][1] += av * b1;
                acc[r][2] += av * b2;
                acc[r][3] += av * b3;
            }
        }
        __syncthreads();
    }

#pragma unroll
    for (int r = 0; r < 8; ++r) {
        int row = row0 + tr * 8 + r;
        if (row < N_NODES) {
            float4 v = make_float4(acc[r][0], acc[r][1], acc[r][2], acc[r][3]);
            *(float4*)&sup[(size_t)row * OUT_F + tc * 4] = v;
        }
    }
}

// ---- CSR gather-reduce + fused tanh ----
// One wave per destination row; lane = output column. wid forced wave-uniform
// so row_ptr / ecol_s / ew_s loads scalarize; 4 independent gathers in flight.
__global__ __launch_bounds__(256) void reduce_kernel(const float* __restrict__ sup,
                                                     const int* __restrict__ row_ptr,
                                                     const int* __restrict__ ecol_s,
                                                     const float* __restrict__ ew_s,
                                                     const int* __restrict__ active,
                                                     float* __restrict__ out) {
    int wid = (blockIdx.x * 256 + threadIdx.x) >> 6;
    wid = __builtin_amdgcn_readfirstlane(wid);
    if (wid >= N_NODES) return;
    const int lane = threadIdx.x & 63;
    const int s = row_ptr[wid];
    const int e = row_ptr[wid + 1];

    float acc = 0.f;
    int j = s;
    for (; j + 4 <= e; j += 4) {
        int   c0 = ecol_s[j],     c1 = ecol_s[j + 1];
        int   c2 = ecol_s[j + 2], c3 = ecol_s[j + 3];
        float w0 = ew_s[j],       w1 = ew_s[j + 1];
        float w2 = ew_s[j + 2],   w3 = ew_s[j + 3];
        float v0 = sup[(size_t)c0 * OUT_F + lane];
        float v1 = sup[(size_t)c1 * OUT_F + lane];
        float v2 = sup[(size_t)c2 * OUT_F + lane];
        float v3 = sup[(size_t)c3 * OUT_F + lane];
        acc += w0 * v0;
        acc += w1 * v1;
        acc += w2 * v2;
        acc += w3 * v3;
    }
    for (; j < e; ++j) acc += ew_s[j] * sup[(size_t)ecol_s[j] * OUT_F + lane];

    float v = (*active) ? tanhf(acc) : acc;
    out[(size_t)wid * OUT_F + lane] = v;
}

extern "C" void kernel_launch(void* const* d_in, const int* in_sizes, int n_in,
                              void* d_out, int out_size, void* d_ws, size_t ws_size,
                              hipStream_t stream) {
    const float* feat = (const float*)d_in[0];
    const float* W    = (const float*)d_in[1];
    const int*   erow = (const int*)d_in[2];
    const int*   ecol = (const int*)d_in[3];
    const float* ew   = (const float*)d_in[4];
    const int*   act  = (const int*)d_in[5];
    float* out = (float*)d_out;

    const int E = in_sizes[2];

    // workspace carve-up
    char* ws = (char*)d_ws;
    float* sup     = (float*)ws;  ws += (size_t)N_NODES * OUT_F * 4;
    int*   hist    = (int*)ws;    ws += (size_t)N_NODES * 4;
    int*   row_ptr = (int*)ws;    ws += (size_t)(N_NODES + 1) * 4;
    int*   cursor  = (int*)ws;    ws += (size_t)N_NODES * 4;
    int*   bsum    = (int*)ws;    ws += 256 * 4;
    int*   bscan   = (int*)ws;    ws += 256 * 4;
    int*   ecol_s  = (int*)ws;    ws += (size_t)E * 4;
    float* ew_s    = (float*)ws;

    // 1) dense projection (independent of CSR build)
    gemm_kernel<<<(N_NODES + 127) / 128, 256, 0, stream>>>(feat, W, sup);

    // 2) CSR build
    zero_hist_kernel<<<NBLK, 256, 0, stream>>>(hist, N_NODES);
    hist_kernel<<<(E + 255) / 256, 256, 0, stream>>>(erow, hist, E);
    partial_kernel<<<NBLK, 256, 0, stream>>>(hist, bsum);
    scan_bsum_kernel<<<1, 256, 0, stream>>>(bsum, bscan, row_ptr);
    scan_local_kernel<<<NBLK, 256, 0, stream>>>(hist, bscan, row_ptr, cursor);
    permute_kernel<<<(E + 255) / 256, 256, 0, stream>>>(erow, ecol, ew, cursor, ecol_s, ew_s, E);

    // 3) gather-reduce with fused tanh
    reduce_kernel<<<(N_NODES * 64) / 256, 256, 0, stream>>>(sup, row_ptr, ecol_s, ew_s, act, out);
}